// Round 5
// baseline (209.985 us; speedup 1.0000x reference)
//
#include <hip/hip_runtime.h>

typedef __bf16 bf16;
typedef bf16 bf16x8 __attribute__((ext_vector_type(8)));
typedef float f32x4 __attribute__((ext_vector_type(4)));
typedef unsigned int u32;

#define PTS 16          // points per block (4 per wave)
#define WREG 6144       // per-wave LDS region bytes
// Per-wave region phases (aliased, same-wave ordered or barrier-protected):
//   phase 0 (stage): [0,6144)  J for 4 pts, identity copy via global_load_lds
//   phase 1 (T):     [0,4800)  12 rows x 400B (row = q*3+i); J read to regs first
//   phase 2 (Y):     [0,3072)  after barrier2, wave-private 16pts x 48 floats
// LDS 4*6144 = 24576 B/block -> 6 blocks/CU (24 waves/CU).
// R5 deltas vs R4: (1) Y stores are NON-TEMPORAL -> they stream past L2/L3 so
// X+J (151MB) stay L3-resident across dispatches (FETCH_SIZE is the signature);
// (2) burst order [J-glds, X, W] + s_waitcnt vmcnt(12): terms start as soon as
// J+X land, W's 12 L2-hit loads keep flying until the wfrag cvt needs them.

__device__ __forceinline__ void gld_lds16(const void* g, void* l) {
    __builtin_amdgcn_global_load_lds(
        (const __attribute__((address_space(1))) u32*)g,
        (__attribute__((address_space(3))) u32*)l, 16, 0, 0);
}

__global__ __launch_bounds__(256, 6)
void affine_linear_fused(const float* __restrict__ X, const float* __restrict__ J,
                         const float* __restrict__ A, const float* __restrict__ Bm,
                         const float* __restrict__ C, float* __restrict__ Y)
{
    __shared__ __attribute__((aligned(128))) unsigned char lds[4 * WREG];

    const int tid  = threadIdx.x;
    const int wave = tid >> 6;
    const int lane = tid & 63;
    const int l16  = lane & 15;
    const int lq   = lane >> 4;       // quad 0..3
    const long bn0 = (long)blockIdx.x * PTS;

    unsigned char* wbase = &lds[wave * WREG];

    // ---- Burst slot 1: J coalesced async stage (6 x 1024B, vmcnt ops 1-6) ----
    {
        const float* jg = J + (bn0 + wave * 4) * 384;
        #pragma unroll
        for (int t = 0; t < 6; ++t)
            gld_lds16(jg + t * 256 + lane * 4, wbase + t * 1024);
    }

    // ---- Burst slot 2: X direct strided loads (vmcnt ops 7-18) ----
    float xv[4][3];
    {
        const float* xg = X + (bn0 + wave * 4) * 192 + lane * 3;
        #pragma unroll
        for (int q = 0; q < 4; ++q) {
            xv[q][0] = xg[q * 192 + 0];
            xv[q][1] = xg[q * 192 + 1];
            xv[q][2] = xg[q * 192 + 2];
        }
    }

    // ---- Burst slot 3: W fragment loads (12 ops, L2/L3-hot; NOT waited here) ----
    // W[f,k]: f = wave*16+l16; k = kk*32 + lq*8 + j; kk<2:A, <4:Bm, else C
    const int f = wave * 16 + l16;
    f32x4 wlo[6], whi[6];
    #pragma unroll
    for (int kk = 0; kk < 6; ++kk) {
        const float* src = (kk < 2) ? A : (kk < 4) ? Bm : C;
        const f32x4* p4 = (const f32x4*)(src + f * 64 + (kk & 1) * 32 + lq * 8);
        wlo[kk] = p4[0];
        whi[kk] = p4[1];
    }

    // Counted wait: drain the 18 oldest (J glds + X); W's 12 stay in flight.
    __asm__ volatile("s_waitcnt vmcnt(12)" ::: "memory");

    // ---- Per point: J from LDS -> terms -> T rows (safe in-order aliasing:
    //      T bytes for point q only overlap J bytes of points <= q) ----
    const float* jlds = (const float*)wbase;
    #pragma unroll
    for (int q = 0; q < 4; ++q) {
        const float* jp = jlds + q * 384 + lane * 6;
        float2 ja  = *(const float2*)(jp + 0);
        float2 jb  = *(const float2*)(jp + 2);
        float2 jc2 = *(const float2*)(jp + 4);
        float a1x = ja.x,  a2x = ja.y;
        float a1y = jb.x,  a2y = jb.y;
        float a1z = jc2.x, a2z = jc2.y;
        float xx = xv[q][0], xy = xv[q][1], xz = xv[q][2];

        float n1sq = a1x*a1x + a1y*a1y + a1z*a1z;
        float inv1 = __builtin_amdgcn_rsqf(fmaxf(n1sq, 1e-24f));  // == 1/max(sqrt,1e-12)
        float b1x = a1x*inv1, b1y = a1y*inv1, b1z = a1z*inv1;
        float dot = b1x*a2x + b1y*a2y + b1z*a2z;
        float ux = a2x - dot*b1x, uy = a2y - dot*b1y, uz = a2z - dot*b1z;
        float n2sq = ux*ux + uy*uy + uz*uz;
        float inv2 = __builtin_amdgcn_rsqf(fmaxf(n2sq, 1e-24f));
        float b2x = ux*inv2, b2y = uy*inv2, b2z = uz*inv2;
        float b3x = b1y*b2z - b1z*b2y;
        float b3y = b1z*b2x - b1x*b2z;
        float b3z = b1x*b2y - b1y*b2x;

        float rt0 = b1x*xx + b1y*xy + b1z*xz;
        float rt1 = b2x*xx + b2y*xy + b2z*xz;
        float rt2 = b3x*xx + b3y*xy + b3z*xz;

        float at0 = b1x*rt0 + b2x*rt1;
        float at1 = b1y*rt0 + b2y*rt1;
        float at2 = b1z*rt0 + b2z*rt1;
        float bt0 = b2x*rt0 - b1x*rt1;
        float bt1 = b2y*rt0 - b1y*rt1;
        float bt2 = b2z*rt0 - b1z*rt1;
        float ct0 = b3x*rt2, ct1 = b3y*rt2, ct2 = b3z*rt2;

        bf16* r0 = (bf16*)(wbase + (q*3 + 0) * 400);
        bf16* r1 = (bf16*)(wbase + (q*3 + 1) * 400);
        bf16* r2 = (bf16*)(wbase + (q*3 + 2) * 400);
        r0[lane] = (bf16)at0; r0[64+lane] = (bf16)bt0; r0[128+lane] = (bf16)ct0;
        r1[lane] = (bf16)at1; r1[64+lane] = (bf16)bt1; r1[128+lane] = (bf16)ct1;
        r2[lane] = (bf16)at2; r2[64+lane] = (bf16)bt2; r2[128+lane] = (bf16)ct2;
    }

    // ---- Convert W to bf16 fragments (compiler inserts the vmcnt wait for W
    //      here -- by now the L2-hit loads have long landed) ----
    bf16x8 wfrag[6];
    #pragma unroll
    for (int kk = 0; kk < 6; ++kk) {
        bf16x8 w;
        w[0] = (bf16)wlo[kk][0]; w[1] = (bf16)wlo[kk][1];
        w[2] = (bf16)wlo[kk][2]; w[3] = (bf16)wlo[kk][3];
        w[4] = (bf16)whi[kk][0]; w[5] = (bf16)whi[kk][1];
        w[6] = (bf16)whi[kk][2]; w[7] = (bf16)whi[kk][3];
        wfrag[kk] = w;
    }

    // barrier 1: publish T (lgkm-only)
    __asm__ volatile("s_waitcnt lgkmcnt(0)" ::: "memory");
    __builtin_amdgcn_s_barrier();

    // ---- MFMA: D[m,f] = sum_k T[m,k] * W[f,k]; T row m = wv*12 + r ----
    const unsigned char* arow[3];
    #pragma unroll
    for (int mt = 0; mt < 3; ++mt) {
        int m  = mt * 16 + l16;
        int wv = m / 12;
        int r  = m - wv * 12;
        arow[mt] = &lds[wv * WREG + r * 400] + lq * 16;
    }
    f32x4 acc[3];
    #pragma unroll
    for (int mt = 0; mt < 3; ++mt) acc[mt] = (f32x4){0.f, 0.f, 0.f, 0.f};
    #pragma unroll
    for (int kk = 0; kk < 6; ++kk) {
        #pragma unroll
        for (int mt = 0; mt < 3; ++mt) {
            bf16x8 af = *(const bf16x8*)(arow[mt] + kk * 64);
            acc[mt] = __builtin_amdgcn_mfma_f32_16x16x32_bf16(af, wfrag[kk], acc[mt], 0, 0, 0);
        }
    }

    // barrier 2: all cross-wave T reads consumed; regions reusable.
    __asm__ volatile("s_waitcnt lgkmcnt(0)" ::: "memory");
    __builtin_amdgcn_s_barrier();

    // ---- Wave-private Y scatter: f-cols [16w,16w+16) => 48 floats per point ----
    float* yw = (float*)wbase;
    #pragma unroll
    for (int mt = 0; mt < 3; ++mt) {
        #pragma unroll
        for (int r = 0; r < 4; ++r) {
            int m  = mt * 16 + lq * 4 + r;
            int wv = m / 12;
            int rr = m - wv * 12;
            int q  = rr / 3;
            int i  = rr - q * 3;
            int p  = wv * 4 + q;
            yw[p * 48 + l16 * 3 + i] = acc[mt][r];
        }
    }

    // ---- Wave-private coalesced writeout, NON-TEMPORAL (keep L3 for inputs) ----
    const f32x4* ysrc = (const f32x4*)yw;
    #pragma unroll
    for (int v = 0; v < 3; ++v) {
        int vi = v * 64 + lane;           // 0..191
        int p  = vi / 12;
        int vo = vi - p * 12;
        f32x4* dst = (f32x4*)(Y + (bn0 + p) * 192 + wave * 48) + vo;
        __builtin_nontemporal_store(ysrc[vi], dst);
    }
}

extern "C" void kernel_launch(void* const* d_in, const int* in_sizes, int n_in,
                              void* d_out, int out_size, void* d_ws, size_t ws_size,
                              hipStream_t stream) {
    const float* X  = (const float*)d_in[0];
    const float* J  = (const float*)d_in[1];
    const float* A  = (const float*)d_in[2];
    const float* Bm = (const float*)d_in[3];
    const float* C  = (const float*)d_in[4];
    float* Y = (float*)d_out;

    const int points = in_sizes[0] / (64 * 3);   // B*N = 65536
    const int blocks = points / PTS;             // 4096
    affine_linear_fused<<<blocks, 256, 0, stream>>>(X, J, A, Bm, C, Y);
}

// Round 8
// 203.833 us; speedup vs baseline: 1.0302x; 1.0302x over previous
//
#include <hip/hip_runtime.h>

typedef __bf16 bf16;
typedef bf16 bf16x8 __attribute__((ext_vector_type(8)));
typedef float f32x4 __attribute__((ext_vector_type(4)));
typedef unsigned int u32;

#define PTS 16          // points per block (4 per wave)
#define WREG 6144       // per-wave LDS region bytes
#define WOFF (4*WREG)   // block-level W region: 64 f-rows x 400B pitch = 25600 B
// Per-wave region phases (aliased, same-wave ordered or barrier-protected):
//   phase 0 (stage): [0,6144)  J for 4 pts, identity copy via global_load_lds
//   phase 1 (T):     [0,4800)  12 rows x 400B (row = q*3+i); per-q read-J-then-write-T
//   phase 2 (Y):     [0,3072)  after barrier2, wave-private 16pts x 48 floats
// Block W region [WOFF, WOFF+25600): W[f][k] bf16, 64 rows x 192 k, 400B pitch
// (pitch 400 => bank step 100 dw == 4 mod 32 => <=2-way on frag reads and T reads).
// LDS total 24576 + 25600 = 50176 -> 3 blocks/CU.
// Theory (unchanged): TA/L1 line-transaction throughput is the wall. W was 768
// divergent lines per WAVE; now 192 coalesced lines per BLOCK (12x 1KB f32x4
// loads) redistributed via LDS. Lines/block ~4200 -> ~1370.
// R7 hardening vs R6 (infra failed 2x on identical source): __syncthreads()
// instead of raw s_barrier+lgkm asm (free here: no vmem outstanding at either
// barrier), and no local pointer array for A/Bm/C.

__device__ __forceinline__ void gld_lds16(const void* g, void* l) {
    __builtin_amdgcn_global_load_lds(
        (const __attribute__((address_space(1))) u32*)g,
        (__attribute__((address_space(3))) u32*)l, 16, 0, 0);
}

__global__ __launch_bounds__(256, 3)
void affine_linear_fused(const float* __restrict__ X, const float* __restrict__ J,
                         const float* __restrict__ A, const float* __restrict__ Bm,
                         const float* __restrict__ C, float* __restrict__ Y)
{
    __shared__ __attribute__((aligned(128))) unsigned char lds[4 * WREG + 25600];

    const int tid  = threadIdx.x;
    const int wave = tid >> 6;
    const int lane = tid & 63;
    const int l16  = lane & 15;
    const int lq   = lane >> 4;       // quad 0..3
    const long bn0 = (long)blockIdx.x * PTS;

    unsigned char* wbase = &lds[wave * WREG];

    // ---- J: coalesced async stage (6 x 1024B, identity copy) ----
    {
        const float* jg = J + (bn0 + wave * 4) * 384;
        #pragma unroll
        for (int t = 0; t < 6; ++t)
            gld_lds16(jg + t * 256 + lane * 4, wbase + t * 1024);
    }

    // ---- X: direct strided loads ----
    float xv[4][3];
    {
        const float* xg = X + (bn0 + wave * 4) * 192 + lane * 3;
        #pragma unroll
        for (int q = 0; q < 4; ++q) {
            xv[q][0] = xg[q * 192 + 0];
            xv[q][1] = xg[q * 192 + 1];
            xv[q][2] = xg[q * 192 + 2];
        }
    }

    // Drain J glds + X (W not yet issued, so vmcnt(0) == "J+X done").
    __asm__ volatile("s_waitcnt vmcnt(0)" ::: "memory");

    // ---- W: cooperative COALESCED load. Thread t owns floats [t*16, t*16+16)
    //      of each matrix: row f = t/4, cols e = (t&3)*16 .. +16. 12x 1KB instrs.
    //      Loads fly during the terms phase (L2-hot); cvt+ds_write after terms. ----
    f32x4 wreg[3][4];
    {
        const int base = tid * 16;
        #pragma unroll
        for (int m = 0; m < 3; ++m) {
            const float* src = (m == 0) ? A : (m == 1) ? Bm : C;
            const f32x4* p4 = (const f32x4*)(src + base);
            wreg[m][0] = p4[0]; wreg[m][1] = p4[1];
            wreg[m][2] = p4[2]; wreg[m][3] = p4[3];
        }
    }

    // ---- Per point: J from LDS -> terms -> T rows (safe in-order aliasing:
    //      J(q) is read before T(q) is written; T(q) never overlaps J(q') for q'>q) ----
    const float* jlds = (const float*)wbase;
    #pragma unroll
    for (int q = 0; q < 4; ++q) {
        const float* jp = jlds + q * 384 + lane * 6;
        float2 ja  = *(const float2*)(jp + 0);
        float2 jb  = *(const float2*)(jp + 2);
        float2 jc2 = *(const float2*)(jp + 4);
        float a1x = ja.x,  a2x = ja.y;
        float a1y = jb.x,  a2y = jb.y;
        float a1z = jc2.x, a2z = jc2.y;
        float xx = xv[q][0], xy = xv[q][1], xz = xv[q][2];

        float n1sq = a1x*a1x + a1y*a1y + a1z*a1z;
        float inv1 = __builtin_amdgcn_rsqf(fmaxf(n1sq, 1e-24f));  // == 1/max(sqrt,1e-12)
        float b1x = a1x*inv1, b1y = a1y*inv1, b1z = a1z*inv1;
        float dot = b1x*a2x + b1y*a2y + b1z*a2z;
        float ux = a2x - dot*b1x, uy = a2y - dot*b1y, uz = a2z - dot*b1z;
        float n2sq = ux*ux + uy*uy + uz*uz;
        float inv2 = __builtin_amdgcn_rsqf(fmaxf(n2sq, 1e-24f));
        float b2x = ux*inv2, b2y = uy*inv2, b2z = uz*inv2;
        float b3x = b1y*b2z - b1z*b2y;
        float b3y = b1z*b2x - b1x*b2z;
        float b3z = b1x*b2y - b1y*b2x;

        float rt0 = b1x*xx + b1y*xy + b1z*xz;
        float rt1 = b2x*xx + b2y*xy + b2z*xz;
        float rt2 = b3x*xx + b3y*xy + b3z*xz;

        float at0 = b1x*rt0 + b2x*rt1;
        float at1 = b1y*rt0 + b2y*rt1;
        float at2 = b1z*rt0 + b2z*rt1;
        float bt0 = b2x*rt0 - b1x*rt1;
        float bt1 = b2y*rt0 - b1y*rt1;
        float bt2 = b2z*rt0 - b1z*rt1;
        float ct0 = b3x*rt2, ct1 = b3y*rt2, ct2 = b3z*rt2;

        bf16* r0 = (bf16*)(wbase + (q*3 + 0) * 400);
        bf16* r1 = (bf16*)(wbase + (q*3 + 1) * 400);
        bf16* r2 = (bf16*)(wbase + (q*3 + 2) * 400);
        r0[lane] = (bf16)at0; r0[64+lane] = (bf16)bt0; r0[128+lane] = (bf16)ct0;
        r1[lane] = (bf16)at1; r1[64+lane] = (bf16)bt1; r1[128+lane] = (bf16)ct1;
        r2[lane] = (bf16)at2; r2[64+lane] = (bf16)bt2; r2[128+lane] = (bf16)ct2;
    }

    // ---- W: convert to bf16, publish to block W region (once per block).
    //      Thread t -> row f = t/4, k-col byte = m*128 + (t&3)*32 (two 16B stores). ----
    {
        unsigned char* wrow = &lds[WOFF + (tid >> 2) * 400];
        #pragma unroll
        for (int m = 0; m < 3; ++m) {
            bf16x8 lo, hi;
            lo[0] = (bf16)wreg[m][0][0]; lo[1] = (bf16)wreg[m][0][1];
            lo[2] = (bf16)wreg[m][0][2]; lo[3] = (bf16)wreg[m][0][3];
            lo[4] = (bf16)wreg[m][1][0]; lo[5] = (bf16)wreg[m][1][1];
            lo[6] = (bf16)wreg[m][1][2]; lo[7] = (bf16)wreg[m][1][3];
            hi[0] = (bf16)wreg[m][2][0]; hi[1] = (bf16)wreg[m][2][1];
            hi[2] = (bf16)wreg[m][2][2]; hi[3] = (bf16)wreg[m][2][3];
            hi[4] = (bf16)wreg[m][3][0]; hi[5] = (bf16)wreg[m][3][1];
            hi[6] = (bf16)wreg[m][3][2]; hi[7] = (bf16)wreg[m][3][3];
            bf16x8* dst = (bf16x8*)(wrow + m * 128 + (tid & 3) * 32);
            dst[0] = lo;
            dst[1] = hi;
        }
    }

    __syncthreads();   // barrier 1: publish T rows + W region

    // ---- W fragments from LDS: f = wave*16+l16, k bytes = kk*64 + lq*16 ----
    const int f = wave * 16 + l16;
    const unsigned char* wb = &lds[WOFF + f * 400];
    bf16x8 wfrag[6];
    #pragma unroll
    for (int kk = 0; kk < 6; ++kk)
        wfrag[kk] = *(const bf16x8*)(wb + kk * 64 + lq * 16);

    // ---- MFMA: D[m,f] = sum_k T[m,k] * W[f,k]; T row m = wv*12 + r ----
    const unsigned char* arow[3];
    #pragma unroll
    for (int mt = 0; mt < 3; ++mt) {
        int m  = mt * 16 + l16;
        int wv = m / 12;
        int r  = m - wv * 12;
        arow[mt] = &lds[wv * WREG + r * 400] + lq * 16;
    }
    f32x4 acc[3];
    #pragma unroll
    for (int mt = 0; mt < 3; ++mt) acc[mt] = (f32x4){0.f, 0.f, 0.f, 0.f};
    #pragma unroll
    for (int kk = 0; kk < 6; ++kk) {
        #pragma unroll
        for (int mt = 0; mt < 3; ++mt) {
            bf16x8 af = *(const bf16x8*)(arow[mt] + kk * 64);
            acc[mt] = __builtin_amdgcn_mfma_f32_16x16x32_bf16(af, wfrag[kk], acc[mt], 0, 0, 0);
        }
    }

    __syncthreads();   // barrier 2: all cross-wave T reads consumed

    // ---- Wave-private Y scatter: f-cols [16w,16w+16) => 48 floats per point ----
    float* yw = (float*)wbase;
    #pragma unroll
    for (int mt = 0; mt < 3; ++mt) {
        #pragma unroll
        for (int r = 0; r < 4; ++r) {
            int m  = mt * 16 + lq * 4 + r;
            int wv = m / 12;
            int rr = m - wv * 12;
            int q  = rr / 3;
            int i  = rr - q * 3;
            int p  = wv * 4 + q;
            yw[p * 48 + l16 * 3 + i] = acc[mt][r];
        }
    }

    // ---- Wave-private coalesced writeout: 16 chunks of 192 B ----
    const f32x4* ysrc = (const f32x4*)yw;
    #pragma unroll
    for (int v = 0; v < 3; ++v) {
        int vi = v * 64 + lane;           // 0..191
        int p  = vi / 12;
        int vo = vi - p * 12;
        f32x4* dst = (f32x4*)(Y + (bn0 + p) * 192 + wave * 48) + vo;
        *dst = ysrc[vi];
    }
}

extern "C" void kernel_launch(void* const* d_in, const int* in_sizes, int n_in,
                              void* d_out, int out_size, void* d_ws, size_t ws_size,
                              hipStream_t stream) {
    const float* X  = (const float*)d_in[0];
    const float* J  = (const float*)d_in[1];
    const float* A  = (const float*)d_in[2];
    const float* Bm = (const float*)d_in[3];
    const float* C  = (const float*)d_in[4];
    float* Y = (float*)d_out;

    const int points = in_sizes[0] / (64 * 3);   // B*N = 65536
    const int blocks = points / PTS;             // 4096
    affine_linear_fused<<<blocks, 256, 0, stream>>>(X, J, A, Bm, C, Y);
}